// Round 1
// baseline (509.086 us; speedup 1.0000x reference)
//
#include <hip/hip_runtime.h>

#define N_PTS 4096
#define C_LIGHT 0.49965409666666664f
#define BN_EPS 1e-3f

// ---------------------------------------------------------------------------
// Fold BN params: for one branch, compute
//   s0 = g0*rsqrt(var0+eps), t0 = be0 - mu0*s0
//   Wf[i][j] = s0[i]*W1[i][j]           (128x256)
//   Bf[j]    = b1[j] + sum_i t0[i]*W1[i][j]
//   S1[j]    = g1*rsqrt(var1+eps), T1[j] = be1 - mu1*S1
// Launched with 1 block x 256 threads, once per branch.
// ---------------------------------------------------------------------------
__global__ __launch_bounds__(256) void fold_kernel(
    const float* __restrict__ W1, const float* __restrict__ b1,
    const float* __restrict__ g0, const float* __restrict__ be0,
    const float* __restrict__ mu0, const float* __restrict__ var0,
    const float* __restrict__ g1, const float* __restrict__ be1,
    const float* __restrict__ mu1, const float* __restrict__ var1,
    float* __restrict__ Wf, float* __restrict__ Bf,
    float* __restrict__ S1, float* __restrict__ T1)
{
    int j = threadIdx.x;  // 0..255
    float s1 = g1[j] / sqrtf(var1[j] + BN_EPS);
    S1[j] = s1;
    T1[j] = be1[j] - mu1[j] * s1;
    float acc = b1[j];
    for (int i = 0; i < 128; ++i) {
        float s0 = g0[i] / sqrtf(var0[i] + BN_EPS);
        float t0 = be0[i] - mu0[i] * s0;
        float w  = W1[i * 256 + j];
        Wf[i * 256 + j] = s0 * w;
        acc = fmaf(t0, w, acc);
    }
    Bf[j] = acc;
}

// ---------------------------------------------------------------------------
// FR branch: fr[row][c] = relu( relu(x@W0+b0) @ Wf + Bf ) * S1 + T1
// rows = B*N = 32768. Block = 256 threads handles 32 rows x 256 cols.
// Wave w owns rows w*8..w*8+7, lane owns 4 contiguous channels.
// ---------------------------------------------------------------------------
__global__ __launch_bounds__(256) void fr_kernel(
    const float* __restrict__ x,    // (B*N, 6)
    const float* __restrict__ W0,   // 6x128
    const float* __restrict__ b0,   // 128
    const float* __restrict__ Wf,   // 128x256 (folded)
    const float* __restrict__ Bf,   // 256
    const float* __restrict__ S1, const float* __restrict__ T1,
    float* __restrict__ fr)         // (B*N, 256)
{
    __shared__ float xs[32][6];
    __shared__ float w0[6][128];
    __shared__ float b0s[128];
    __shared__ float hid[32][128];
    __shared__ float wt[16][256];

    int t = threadIdx.x;
    long row0 = (long)blockIdx.x * 32;

    if (t < 192) xs[t / 6][t % 6] = x[row0 * 6 + t];
    for (int i = t; i < 768; i += 256) w0[i >> 7][i & 127] = W0[i];
    if (t < 128) b0s[t] = b0[t];
    __syncthreads();

    // hidden = relu(x@W0 + b0): 32 rows x 128, by float4 channel groups
    for (int idx = t; idx < 32 * 32; idx += 256) {
        int r = idx >> 5, c4 = (idx & 31) << 2;
        float a0 = b0s[c4], a1 = b0s[c4 + 1], a2 = b0s[c4 + 2], a3 = b0s[c4 + 3];
#pragma unroll
        for (int i = 0; i < 6; ++i) {
            float xv = xs[r][i];
            a0 = fmaf(xv, w0[i][c4],     a0);
            a1 = fmaf(xv, w0[i][c4 + 1], a1);
            a2 = fmaf(xv, w0[i][c4 + 2], a2);
            a3 = fmaf(xv, w0[i][c4 + 3], a3);
        }
        float4 h4;
        h4.x = fmaxf(a0, 0.f); h4.y = fmaxf(a1, 0.f);
        h4.z = fmaxf(a2, 0.f); h4.w = fmaxf(a3, 0.f);
        *(float4*)&hid[r][c4] = h4;
    }

    int wv = t >> 6, lane = t & 63;
    int c0 = lane * 4;
    int r0 = wv * 8;

    float acc[8][4];
    {
        float4 bf4 = *(const float4*)&Bf[c0];
#pragma unroll
        for (int r = 0; r < 8; ++r) {
            acc[r][0] = bf4.x; acc[r][1] = bf4.y; acc[r][2] = bf4.z; acc[r][3] = bf4.w;
        }
    }

    for (int ch = 0; ch < 8; ++ch) {
        __syncthreads();
        const float4* src = (const float4*)(Wf + ch * 16 * 256);
        float4* dst = (float4*)&wt[0][0];
        for (int i = t; i < 1024; i += 256) dst[i] = src[i];
        __syncthreads();
#pragma unroll
        for (int kk4 = 0; kk4 < 4; ++kk4) {
            float4 h[8];
#pragma unroll
            for (int r = 0; r < 8; ++r)
                h[r] = *(const float4*)&hid[r0 + r][ch * 16 + kk4 * 4];
            float4 w4[4];
#pragma unroll
            for (int q = 0; q < 4; ++q)
                w4[q] = *(const float4*)&wt[kk4 * 4 + q][c0];
#pragma unroll
            for (int r = 0; r < 8; ++r) {
#pragma unroll
                for (int q = 0; q < 4; ++q) {
                    float hq = (q == 0) ? h[r].x : (q == 1) ? h[r].y : (q == 2) ? h[r].z : h[r].w;
                    acc[r][0] = fmaf(hq, w4[q].x, acc[r][0]);
                    acc[r][1] = fmaf(hq, w4[q].y, acc[r][1]);
                    acc[r][2] = fmaf(hq, w4[q].z, acc[r][2]);
                    acc[r][3] = fmaf(hq, w4[q].w, acc[r][3]);
                }
            }
        }
    }

    float4 s14 = *(const float4*)&S1[c0];
    float4 t14 = *(const float4*)&T1[c0];
#pragma unroll
    for (int r = 0; r < 8; ++r) {
        float4 o;
        o.x = fmaf(fmaxf(acc[r][0], 0.f), s14.x, t14.x);
        o.y = fmaf(fmaxf(acc[r][1], 0.f), s14.y, t14.y);
        o.z = fmaf(fmaxf(acc[r][2], 0.f), s14.z, t14.z);
        o.w = fmaf(fmaxf(acc[r][3], 0.f), s14.w, t14.w);
        *(float4*)&fr[(row0 + r0 + r) * 256 + c0] = o;
    }
}

// ---------------------------------------------------------------------------
// Fused H-layer + M-branch + A-layer.
// Block = 256 threads handles TN=4 n-positions of one batch b.
// Rows = 4 n x 9 k = 36. Wave w owns n-local w (9 k-rows), lane owns 4 chans.
// out[b,n,c] = max_k ( (relu(hid_row@Wf+Bf)*S1+T1) * fr[b, n+k-4, c] )
// ---------------------------------------------------------------------------
__global__ __launch_bounds__(256) void fused_kernel(
    const float* __restrict__ x,    // (B, N, 6)
    const float* __restrict__ W0,   // 12x128
    const float* __restrict__ b0,   // 128
    const float* __restrict__ Wf,   // 128x256 folded
    const float* __restrict__ Bf,   // 256
    const float* __restrict__ S1, const float* __restrict__ T1,
    const float* __restrict__ fr,   // (B, N, 256)
    float* __restrict__ out)        // (B, N, 256)
{
    __shared__ float xs[12][6];      // n0-4 .. n0+7, zero-padded OOB
    __shared__ float w0[12][128];
    __shared__ float b0s[128];
    __shared__ float hf[36][12];     // H features
    __shared__ float hid[36][128];
    __shared__ float wt[16][256];    // W-chunk

    int t = threadIdx.x;
    int bn = blockIdx.x;                  // over B * N/4
    int b  = bn >> 10;                    // N/4 = 1024
    int n0 = (bn & 1023) << 2;
    const float* xb = x + (long)b * N_PTS * 6;

    if (t < 72) {
        int rr = t / 6, cc = t % 6;
        int n = n0 - 4 + rr;
        xs[rr][cc] = (n >= 0 && n < N_PTS) ? xb[n * 6 + cc] : 0.f;
    }
    for (int i = t; i < 1536; i += 256) w0[i >> 7][i & 127] = W0[i];
    if (t < 128) b0s[t] = b0[t];
    __syncthreads();

    // H features: 36 rows, 12 feats each
    if (t < 36) {
        int nl = t / 9, k = t % 9;
        const float* self = xs[nl + 4];
        const float* nb   = xs[nl + k];
        int nbn = n0 + nl + k - 4;
        float msk = (nbn >= 0 && nbn < N_PTS) ? 1.f : 0.f;
        float dt = (nb[0] - self[0]) * msk;
        float dx = (nb[3] - self[3]) * msk;
        float dy = (nb[4] - self[4]) * msk;
        float dz = (nb[5] - self[5]) * msk;
        float eu2 = dx * dx + dy * dy + dz * dz;
        hf[t][0]  = nb[0];  // win2(t)
        hf[t][1]  = nb[3];  // win2(px)
        hf[t][2]  = nb[4];  // win2(py)
        hf[t][3]  = nb[5];  // win2(pz)
        hf[t][4]  = nb[1];  // win2(c)
        hf[t][5]  = nb[2];  // win2(a)
        hf[t][6]  = dt;
        hf[t][7]  = dx;
        hf[t][8]  = dy;
        hf[t][9]  = dz;
        hf[t][10] = sqrtf(eu2);
        float cdt = C_LIGHT * dt;
        hf[t][11] = cdt * cdt - eu2;
    }
    __syncthreads();

    // hidden = relu(hf@W0 + b0): 36 rows x 128
    for (int idx = t; idx < 36 * 32; idx += 256) {
        int r = idx >> 5, c4 = (idx & 31) << 2;
        float a0 = b0s[c4], a1 = b0s[c4 + 1], a2 = b0s[c4 + 2], a3 = b0s[c4 + 3];
#pragma unroll
        for (int i = 0; i < 12; ++i) {
            float hv = hf[r][i];
            a0 = fmaf(hv, w0[i][c4],     a0);
            a1 = fmaf(hv, w0[i][c4 + 1], a1);
            a2 = fmaf(hv, w0[i][c4 + 2], a2);
            a3 = fmaf(hv, w0[i][c4 + 3], a3);
        }
        float4 h4;
        h4.x = fmaxf(a0, 0.f); h4.y = fmaxf(a1, 0.f);
        h4.z = fmaxf(a2, 0.f); h4.w = fmaxf(a3, 0.f);
        *(float4*)&hid[r][c4] = h4;
    }

    int wv = t >> 6, lane = t & 63;
    int c0 = lane * 4;
    int r0 = wv * 9;   // 9 k-rows for n-local wv

    float acc[9][4];
    {
        float4 bf4 = *(const float4*)&Bf[c0];
#pragma unroll
        for (int k = 0; k < 9; ++k) {
            acc[k][0] = bf4.x; acc[k][1] = bf4.y; acc[k][2] = bf4.z; acc[k][3] = bf4.w;
        }
    }

    for (int ch = 0; ch < 8; ++ch) {
        __syncthreads();
        const float4* src = (const float4*)(Wf + ch * 16 * 256);
        float4* dst = (float4*)&wt[0][0];
        for (int i = t; i < 1024; i += 256) dst[i] = src[i];
        __syncthreads();
#pragma unroll
        for (int kk4 = 0; kk4 < 4; ++kk4) {
            float4 h[9];
#pragma unroll
            for (int k = 0; k < 9; ++k)
                h[k] = *(const float4*)&hid[r0 + k][ch * 16 + kk4 * 4];
            float4 w4[4];
#pragma unroll
            for (int q = 0; q < 4; ++q)
                w4[q] = *(const float4*)&wt[kk4 * 4 + q][c0];
#pragma unroll
            for (int k = 0; k < 9; ++k) {
#pragma unroll
                for (int q = 0; q < 4; ++q) {
                    float hq = (q == 0) ? h[k].x : (q == 1) ? h[k].y : (q == 2) ? h[k].z : h[k].w;
                    acc[k][0] = fmaf(hq, w4[q].x, acc[k][0]);
                    acc[k][1] = fmaf(hq, w4[q].y, acc[k][1]);
                    acc[k][2] = fmaf(hq, w4[q].z, acc[k][2]);
                    acc[k][3] = fmaf(hq, w4[q].w, acc[k][3]);
                }
            }
        }
    }

    // Epilogue: m = relu(acc)*S1+T1; T = m * fr[n+k-4]; out = max_k T
    int n = n0 + wv;
    float4 s14 = *(const float4*)&S1[c0];
    float4 t14 = *(const float4*)&T1[c0];
    const float* frb = fr + (long)b * N_PTS * 256;
    float4 best;
#pragma unroll
    for (int k = 0; k < 9; ++k) {
        int nbn = n + k - 4;
        float4 f4 = make_float4(0.f, 0.f, 0.f, 0.f);
        if (nbn >= 0 && nbn < N_PTS)
            f4 = *(const float4*)&frb[(long)nbn * 256 + c0];
        float4 T;
        T.x = fmaf(fmaxf(acc[k][0], 0.f), s14.x, t14.x) * f4.x;
        T.y = fmaf(fmaxf(acc[k][1], 0.f), s14.y, t14.y) * f4.y;
        T.z = fmaf(fmaxf(acc[k][2], 0.f), s14.z, t14.z) * f4.z;
        T.w = fmaf(fmaxf(acc[k][3], 0.f), s14.w, t14.w) * f4.w;
        if (k == 0) best = T;
        else {
            best.x = fmaxf(best.x, T.x);
            best.y = fmaxf(best.y, T.y);
            best.z = fmaxf(best.z, T.z);
            best.w = fmaxf(best.w, T.w);
        }
    }
    *(float4*)&out[((long)b * N_PTS + n) * 256 + c0] = best;
}

// ---------------------------------------------------------------------------
extern "C" void kernel_launch(void* const* d_in, const int* in_sizes, int n_in,
                              void* d_out, int out_size, void* d_ws, size_t ws_size,
                              hipStream_t stream)
{
    const float* x = (const float*)d_in[0];
    // dict order: x, then for i in {0,1}: m_W, f_W, m_b, f_b, m_g, f_g,
    //                                     m_be, f_be, m_mu, f_mu, m_var, f_var
    const float* m_W0  = (const float*)d_in[1];
    const float* f_W0  = (const float*)d_in[2];
    const float* m_b0  = (const float*)d_in[3];
    const float* f_b0  = (const float*)d_in[4];
    const float* m_g0  = (const float*)d_in[5];
    const float* f_g0  = (const float*)d_in[6];
    const float* m_be0 = (const float*)d_in[7];
    const float* f_be0 = (const float*)d_in[8];
    const float* m_mu0 = (const float*)d_in[9];
    const float* f_mu0 = (const float*)d_in[10];
    const float* m_var0= (const float*)d_in[11];
    const float* f_var0= (const float*)d_in[12];
    const float* m_W1  = (const float*)d_in[13];
    const float* f_W1  = (const float*)d_in[14];
    const float* m_b1  = (const float*)d_in[15];
    const float* f_b1  = (const float*)d_in[16];
    const float* m_g1  = (const float*)d_in[17];
    const float* f_g1  = (const float*)d_in[18];
    const float* m_be1 = (const float*)d_in[19];
    const float* f_be1 = (const float*)d_in[20];
    const float* m_mu1 = (const float*)d_in[21];
    const float* f_mu1 = (const float*)d_in[22];
    const float* m_var1= (const float*)d_in[23];
    const float* f_var1= (const float*)d_in[24];

    float* ws  = (float*)d_ws;
    float* fr  = ws;                        // 8*4096*256 = 8388608 floats
    float* mWf = ws + 8388608;              // 128*256
    float* mBf = mWf + 32768;               // 256
    float* mS1 = mBf + 256;
    float* mT1 = mS1 + 256;
    float* fWf = mT1 + 256;                 // 128*256
    float* fBf = fWf + 32768;
    float* fS1 = fBf + 256;
    float* fT1 = fS1 + 256;

    fold_kernel<<<1, 256, 0, stream>>>(m_W1, m_b1, m_g0, m_be0, m_mu0, m_var0,
                                       m_g1, m_be1, m_mu1, m_var1,
                                       mWf, mBf, mS1, mT1);
    fold_kernel<<<1, 256, 0, stream>>>(f_W1, f_b1, f_g0, f_be0, f_mu0, f_var0,
                                       f_g1, f_be1, f_mu1, f_var1,
                                       fWf, fBf, fS1, fT1);

    fr_kernel<<<8 * N_PTS / 32, 256, 0, stream>>>(x, f_W0, f_b0, fWf, fBf, fS1, fT1, fr);

    fused_kernel<<<8 * N_PTS / 4, 256, 0, stream>>>(x, m_W0, m_b0, mWf, mBf, mS1, mT1,
                                                    fr, (float*)d_out);
}

// Round 2
// 234.896 us; speedup vs baseline: 2.1673x; 2.1673x over previous
//
#include <hip/hip_runtime.h>

#define N_PTS 4096
#define C_LIGHT 0.49965409666666664f
#define BN_EPS 1e-3f

typedef __attribute__((ext_vector_type(8))) short short8;
typedef __attribute__((ext_vector_type(4))) float f32x4;

static __device__ __forceinline__ unsigned short f2bf(float f) {
    unsigned u = __float_as_uint(f);
    u += 0x7FFFu + ((u >> 16) & 1u);   // round-to-nearest-even
    return (unsigned short)(u >> 16);
}
static __device__ __forceinline__ float bf2f(unsigned short h) {
    return __uint_as_float(((unsigned)h) << 16);
}

// ---------------------------------------------------------------------------
// Fold: per branch (blockIdx 0=m, 1=f) compute
//   s0,t0; Bf = b1 + t0@W1; S1,T1; and Wf = diag(s0)@W1 split into bf16
//   hi/lo stored in B-fragment order: [ct(16)][ks(4)][lane(64)][j(8)]
//   element = Wf[ks*32 + (lane>>4)*8 + j][ct*16 + (lane&15)]
// ---------------------------------------------------------------------------
__global__ __launch_bounds__(256) void fold_kernel(
    const float* __restrict__ mW1, const float* __restrict__ mb1,
    const float* __restrict__ mg0, const float* __restrict__ mbe0,
    const float* __restrict__ mmu0, const float* __restrict__ mvar0,
    const float* __restrict__ mg1, const float* __restrict__ mbe1,
    const float* __restrict__ mmu1, const float* __restrict__ mvar1,
    const float* __restrict__ fW1p, const float* __restrict__ fb1,
    const float* __restrict__ fg0, const float* __restrict__ fbe0,
    const float* __restrict__ fmu0, const float* __restrict__ fvar0,
    const float* __restrict__ fg1, const float* __restrict__ fbe1,
    const float* __restrict__ fmu1, const float* __restrict__ fvar1,
    float* __restrict__ mBf, float* __restrict__ mS1, float* __restrict__ mT1,
    unsigned short* __restrict__ mWhi, unsigned short* __restrict__ mWlo,
    float* __restrict__ fBf, float* __restrict__ fS1, float* __restrict__ fT1,
    unsigned short* __restrict__ fWhi, unsigned short* __restrict__ fWlo)
{
    int br = blockIdx.x;
    const float* W1  = br ? fW1p : mW1;
    const float* b1  = br ? fb1  : mb1;
    const float* g0  = br ? fg0  : mg0;
    const float* be0 = br ? fbe0 : mbe0;
    const float* mu0 = br ? fmu0 : mmu0;
    const float* var0= br ? fvar0: mvar0;
    const float* g1  = br ? fg1  : mg1;
    const float* be1 = br ? fbe1 : mbe1;
    const float* mu1 = br ? fmu1 : mmu1;
    const float* var1= br ? fvar1: mvar1;
    float* Bf = br ? fBf : mBf;
    float* S1 = br ? fS1 : mS1;
    float* T1 = br ? fT1 : mT1;
    unsigned short* Whi = br ? fWhi : mWhi;
    unsigned short* Wlo = br ? fWlo : mWlo;

    __shared__ float s0s[128], t0s[128];
    int t = threadIdx.x;
    if (t < 128) {
        float s = g0[t] / sqrtf(var0[t] + BN_EPS);
        s0s[t] = s;
        t0s[t] = be0[t] - mu0[t] * s;
    }
    __syncthreads();

    {
        float s1 = g1[t] / sqrtf(var1[t] + BN_EPS);
        S1[t] = s1;
        T1[t] = be1[t] - mu1[t] * s1;
        float acc = b1[t];
        for (int i = 0; i < 128; ++i) acc = fmaf(t0s[i], W1[i * 256 + t], acc);
        Bf[t] = acc;
    }

    for (int e = t; e < 32768; e += 256) {
        int j = e & 7, l = (e >> 3) & 63, ks = (e >> 9) & 3, ct = e >> 11;
        int i = ks * 32 + (l >> 4) * 8 + j;
        int c = ct * 16 + (l & 15);
        float w = s0s[i] * W1[i * 256 + c];
        unsigned short hi = f2bf(w);
        unsigned short lo = f2bf(w - bf2f(hi));
        Whi[e] = hi;
        Wlo[e] = lo;
    }
}

// ---------------------------------------------------------------------------
// FR branch (MFMA): 64 rows/block, K=128 sliced in 4 ks chunks of 32.
// hidden slice (fp32 VALU) -> LDS in A-frag layout -> 3-product bf16 MFMA.
// ---------------------------------------------------------------------------
__global__ __launch_bounds__(256, 2) void fr_kernel(
    const float* __restrict__ x,    // (32768, 6)
    const float* __restrict__ W0,   // 6x128
    const float* __restrict__ b0,
    const short8* __restrict__ WfHi, const short8* __restrict__ WfLo,
    const float* __restrict__ Bf, const float* __restrict__ S1,
    const float* __restrict__ T1,
    float* __restrict__ fr)
{
    __shared__ float xs[64][6];
    __shared__ __attribute__((aligned(16))) float w0s[6][136];
    __shared__ __attribute__((aligned(16))) float b0s[128];
    __shared__ __attribute__((aligned(16))) unsigned short hAhi[4 * 64 * 8];
    __shared__ __attribute__((aligned(16))) unsigned short hAlo[4 * 64 * 8];

    int t = threadIdx.x;
    long row0 = (long)blockIdx.x * 64;

    for (int i = t; i < 384; i += 256) xs[i / 6][i % 6] = x[row0 * 6 + i];
    for (int i = t; i < 768; i += 256) w0s[i >> 7][i & 127] = W0[i];
    if (t < 128) b0s[t] = b0[t];

    int lane = t & 63, wv = t >> 6;
    int laneN = lane & 15, laneH = lane >> 4;
    int cg = t & 7;

    float bfv[4], s1v[4], t1v[4];
    int colc[4];
#pragma unroll
    for (int c = 0; c < 4; ++c) {
        colc[c] = (wv * 4 + c) * 16 + laneN;
        bfv[c] = Bf[colc[c]];
        s1v[c] = S1[colc[c]];
        t1v[c] = T1[colc[c]];
    }
    f32x4 acc[4][4];
#pragma unroll
    for (int mt = 0; mt < 4; ++mt)
#pragma unroll
        for (int c = 0; c < 4; ++c) {
            f32x4 z = {bfv[c], bfv[c], bfv[c], bfv[c]};
            acc[mt][c] = z;
        }
    __syncthreads();

    for (int ks = 0; ks < 4; ++ks) {
        int k0 = ks * 32 + cg * 4;
        float4 wreg[6];
#pragma unroll
        for (int i = 0; i < 6; ++i) wreg[i] = *(const float4*)&w0s[i][k0];
        float4 bq = *(const float4*)&b0s[k0];

        for (int idx = t; idx < 512; idx += 256) {
            int row = idx >> 3;   // 0..63 ; (idx&7)==cg
            float a0 = bq.x, a1 = bq.y, a2 = bq.z, a3 = bq.w;
#pragma unroll
            for (int i = 0; i < 6; ++i) {
                float hv = xs[row][i];
                a0 = fmaf(hv, wreg[i].x, a0);
                a1 = fmaf(hv, wreg[i].y, a1);
                a2 = fmaf(hv, wreg[i].z, a2);
                a3 = fmaf(hv, wreg[i].w, a3);
            }
            a0 = fmaxf(a0, 0.f); a1 = fmaxf(a1, 0.f);
            a2 = fmaxf(a2, 0.f); a3 = fmaxf(a3, 0.f);
            unsigned short h0 = f2bf(a0), h1 = f2bf(a1), h2 = f2bf(a2), h3 = f2bf(a3);
            unsigned short l0 = f2bf(a0 - bf2f(h0)), l1 = f2bf(a1 - bf2f(h1));
            unsigned short l2 = f2bf(a2 - bf2f(h2)), l3 = f2bf(a3 - bf2f(h3));
            int mt = row >> 4, nl = row & 15;
            int base = (mt * 64 + (cg >> 1) * 16 + nl) * 8 + (cg & 1) * 4;
            uint2 hv2; hv2.x = (unsigned)h0 | ((unsigned)h1 << 16);
            hv2.y = (unsigned)h2 | ((unsigned)h3 << 16);
            *(uint2*)&hAhi[base] = hv2;
            uint2 lv2; lv2.x = (unsigned)l0 | ((unsigned)l1 << 16);
            lv2.y = (unsigned)l2 | ((unsigned)l3 << 16);
            *(uint2*)&hAlo[base] = lv2;
        }
        __syncthreads();

        short8 Bhi[4], Blo[4];
#pragma unroll
        for (int c = 0; c < 4; ++c) {
            int fo = ((wv * 4 + c) * 4 + ks) * 64 + lane;
            Bhi[c] = WfHi[fo];
            Blo[c] = WfLo[fo];
        }
#pragma unroll
        for (int mt = 0; mt < 4; ++mt) {
            short8 Ahi = *(const short8*)&hAhi[(mt * 64 + lane) * 8];
            short8 Alo = *(const short8*)&hAlo[(mt * 64 + lane) * 8];
#pragma unroll
            for (int c = 0; c < 4; ++c) {
                f32x4 a = acc[mt][c];
                a = __builtin_amdgcn_mfma_f32_16x16x32_bf16(Alo, Bhi[c], a, 0, 0, 0);
                a = __builtin_amdgcn_mfma_f32_16x16x32_bf16(Ahi, Blo[c], a, 0, 0, 0);
                a = __builtin_amdgcn_mfma_f32_16x16x32_bf16(Ahi, Bhi[c], a, 0, 0, 0);
                acc[mt][c] = a;
            }
        }
        __syncthreads();
    }

#pragma unroll
    for (int c = 0; c < 4; ++c)
#pragma unroll
        for (int mt = 0; mt < 4; ++mt)
#pragma unroll
            for (int r = 0; r < 4; ++r) {
                float y = fmaf(fmaxf(acc[mt][c][r], 0.f), s1v[c], t1v[c]);
                fr[(row0 + mt * 16 + laneH * 4 + r) * 256 + colc[c]] = y;
            }
}

// ---------------------------------------------------------------------------
// Fused H + M-branch + A-layer (MFMA).
// Block: 256 thr, 16 n-positions, 144 rows = 9 M-tiles (tile index == k).
// max over k == elementwise max over the 9 accumulator tiles.
// ---------------------------------------------------------------------------
__global__ __launch_bounds__(256, 2) void fused_kernel(
    const float* __restrict__ x,    // (B, N, 6)
    const float* __restrict__ W0,   // 12x128
    const float* __restrict__ b0,
    const short8* __restrict__ WfHi, const short8* __restrict__ WfLo,
    const float* __restrict__ Bf, const float* __restrict__ S1,
    const float* __restrict__ T1,
    const float* __restrict__ fr,   // (B, N, 256)
    float* __restrict__ out)        // (B, N, 256)
{
    __shared__ float xs[24][6];
    __shared__ float hf_s[144][12];
    __shared__ __attribute__((aligned(16))) float w0s[12][136];
    __shared__ __attribute__((aligned(16))) float b0s[128];
    __shared__ __attribute__((aligned(16))) unsigned short hAhi[9 * 64 * 8];
    __shared__ __attribute__((aligned(16))) unsigned short hAlo[9 * 64 * 8];

    int t = threadIdx.x;
    int bn = blockIdx.x;
    int b  = bn >> 8;               // 256 blocks per batch
    int n0 = (bn & 255) << 4;
    const float* xb = x + (long)b * N_PTS * 6;

    if (t < 144) {                  // 24 rows x 6 cols
        int rr = t / 6, cc = t % 6;
        int n = n0 - 4 + rr;
        xs[rr][cc] = (n >= 0 && n < N_PTS) ? xb[n * 6 + cc] : 0.f;
    }
    for (int i = t; i < 12 * 128; i += 256) w0s[i >> 7][i & 127] = W0[i];
    if (t < 128) b0s[t] = b0[t];
    __syncthreads();

    if (t < 144) {                  // row = kt*16 + nl
        int kt = t >> 4, nl = t & 15;
        const float* self = xs[nl + 4];
        const float* nb   = xs[nl + kt];
        int nbn = n0 + nl + kt - 4;
        float msk = (nbn >= 0 && nbn < N_PTS) ? 1.f : 0.f;
        float dt = (nb[0] - self[0]) * msk;
        float dx = (nb[3] - self[3]) * msk;
        float dy = (nb[4] - self[4]) * msk;
        float dz = (nb[5] - self[5]) * msk;
        float eu2 = dx * dx + dy * dy + dz * dz;
        hf_s[t][0]  = nb[0];
        hf_s[t][1]  = nb[3];
        hf_s[t][2]  = nb[4];
        hf_s[t][3]  = nb[5];
        hf_s[t][4]  = nb[1];
        hf_s[t][5]  = nb[2];
        hf_s[t][6]  = dt;
        hf_s[t][7]  = dx;
        hf_s[t][8]  = dy;
        hf_s[t][9]  = dz;
        hf_s[t][10] = sqrtf(eu2);
        float cdt = C_LIGHT * dt;
        hf_s[t][11] = cdt * cdt - eu2;
    }

    int lane = t & 63, wv = t >> 6;
    int laneN = lane & 15, laneH = lane >> 4;
    int cg = t & 7;

    float bfv[4], s1v[4], t1v[4];
    int colc[4];
#pragma unroll
    for (int c = 0; c < 4; ++c) {
        colc[c] = (wv * 4 + c) * 16 + laneN;
        bfv[c] = Bf[colc[c]];
        s1v[c] = S1[colc[c]];
        t1v[c] = T1[colc[c]];
    }
    f32x4 acc[9][4];
#pragma unroll
    for (int kt = 0; kt < 9; ++kt)
#pragma unroll
        for (int c = 0; c < 4; ++c) {
            f32x4 z = {bfv[c], bfv[c], bfv[c], bfv[c]};
            acc[kt][c] = z;
        }
    __syncthreads();

    for (int ks = 0; ks < 4; ++ks) {
        int k0 = ks * 32 + cg * 4;
        float4 wreg[12];
#pragma unroll
        for (int i = 0; i < 12; ++i) wreg[i] = *(const float4*)&w0s[i][k0];
        float4 bq = *(const float4*)&b0s[k0];

        for (int idx = t; idx < 1152; idx += 256) {
            int row = idx >> 3;     // 0..143 ; (idx&7)==cg
            float a0 = bq.x, a1 = bq.y, a2 = bq.z, a3 = bq.w;
#pragma unroll
            for (int i = 0; i < 12; ++i) {
                float hv = hf_s[row][i];
                a0 = fmaf(hv, wreg[i].x, a0);
                a1 = fmaf(hv, wreg[i].y, a1);
                a2 = fmaf(hv, wreg[i].z, a2);
                a3 = fmaf(hv, wreg[i].w, a3);
            }
            a0 = fmaxf(a0, 0.f); a1 = fmaxf(a1, 0.f);
            a2 = fmaxf(a2, 0.f); a3 = fmaxf(a3, 0.f);
            unsigned short h0 = f2bf(a0), h1 = f2bf(a1), h2 = f2bf(a2), h3 = f2bf(a3);
            unsigned short l0 = f2bf(a0 - bf2f(h0)), l1 = f2bf(a1 - bf2f(h1));
            unsigned short l2 = f2bf(a2 - bf2f(h2)), l3 = f2bf(a3 - bf2f(h3));
            int kt = row >> 4, nl = row & 15;
            int base = (kt * 64 + (cg >> 1) * 16 + nl) * 8 + (cg & 1) * 4;
            uint2 hv2; hv2.x = (unsigned)h0 | ((unsigned)h1 << 16);
            hv2.y = (unsigned)h2 | ((unsigned)h3 << 16);
            *(uint2*)&hAhi[base] = hv2;
            uint2 lv2; lv2.x = (unsigned)l0 | ((unsigned)l1 << 16);
            lv2.y = (unsigned)l2 | ((unsigned)l3 << 16);
            *(uint2*)&hAlo[base] = lv2;
        }
        __syncthreads();

        short8 Bhi[4], Blo[4];
#pragma unroll
        for (int c = 0; c < 4; ++c) {
            int fo = ((wv * 4 + c) * 4 + ks) * 64 + lane;
            Bhi[c] = WfHi[fo];
            Blo[c] = WfLo[fo];
        }
#pragma unroll
        for (int kt = 0; kt < 9; ++kt) {
            short8 Ahi = *(const short8*)&hAhi[(kt * 64 + lane) * 8];
            short8 Alo = *(const short8*)&hAlo[(kt * 64 + lane) * 8];
#pragma unroll
            for (int c = 0; c < 4; ++c) {
                f32x4 a = acc[kt][c];
                a = __builtin_amdgcn_mfma_f32_16x16x32_bf16(Alo, Bhi[c], a, 0, 0, 0);
                a = __builtin_amdgcn_mfma_f32_16x16x32_bf16(Ahi, Blo[c], a, 0, 0, 0);
                a = __builtin_amdgcn_mfma_f32_16x16x32_bf16(Ahi, Bhi[c], a, 0, 0, 0);
                acc[kt][c] = a;
            }
        }
        __syncthreads();
    }

    // Epilogue: m = relu(acc)*S1+T1; T = m * fr[n+kt-4]; out = max_kt T
    const float* frb = fr + ((long)b << 20);
    float* outb = out + ((long)b << 20);
#pragma unroll
    for (int c = 0; c < 4; ++c) {
        float best[4];
#pragma unroll
        for (int kt = 0; kt < 9; ++kt) {
#pragma unroll
            for (int r = 0; r < 4; ++r) {
                int nl = laneH * 4 + r;
                int nbn = n0 + nl + kt - 4;
                float f = 0.f;
                if (nbn >= 0 && nbn < N_PTS) f = frb[nbn * 256 + colc[c]];
                float m = fmaf(fmaxf(acc[kt][c][r], 0.f), s1v[c], t1v[c]);
                float T = m * f;
                best[r] = (kt == 0) ? T : fmaxf(best[r], T);
            }
        }
#pragma unroll
        for (int r = 0; r < 4; ++r)
            outb[(n0 + laneH * 4 + r) * 256 + colc[c]] = best[r];
    }
}

// ---------------------------------------------------------------------------
extern "C" void kernel_launch(void* const* d_in, const int* in_sizes, int n_in,
                              void* d_out, int out_size, void* d_ws, size_t ws_size,
                              hipStream_t stream)
{
    const float* x = (const float*)d_in[0];
    const float* m_W0  = (const float*)d_in[1];
    const float* f_W0  = (const float*)d_in[2];
    const float* m_b0  = (const float*)d_in[3];
    const float* f_b0  = (const float*)d_in[4];
    const float* m_g0  = (const float*)d_in[5];
    const float* f_g0  = (const float*)d_in[6];
    const float* m_be0 = (const float*)d_in[7];
    const float* f_be0 = (const float*)d_in[8];
    const float* m_mu0 = (const float*)d_in[9];
    const float* f_mu0 = (const float*)d_in[10];
    const float* m_var0= (const float*)d_in[11];
    const float* f_var0= (const float*)d_in[12];
    const float* m_W1  = (const float*)d_in[13];
    const float* f_W1  = (const float*)d_in[14];
    const float* m_b1  = (const float*)d_in[15];
    const float* f_b1  = (const float*)d_in[16];
    const float* m_g1  = (const float*)d_in[17];
    const float* f_g1  = (const float*)d_in[18];
    const float* m_be1 = (const float*)d_in[19];
    const float* f_be1 = (const float*)d_in[20];
    const float* m_mu1 = (const float*)d_in[21];
    const float* f_mu1 = (const float*)d_in[22];
    const float* m_var1= (const float*)d_in[23];
    const float* f_var1= (const float*)d_in[24];

    char* wsb = (char*)d_ws;
    float* fr  = (float*)wsb;                       // 8*4096*256 f32 = 33,554,432 B
    float* mBf = (float*)(wsb + 33554432);
    float* mS1 = mBf + 256;
    float* mT1 = mS1 + 256;
    float* fBf = mT1 + 256;
    float* fS1 = fBf + 256;
    float* fT1 = fS1 + 256;
    unsigned short* mWhi = (unsigned short*)(fT1 + 256);  // 32768 each
    unsigned short* mWlo = mWhi + 32768;
    unsigned short* fWhi = mWlo + 32768;
    unsigned short* fWlo = fWhi + 32768;

    fold_kernel<<<2, 256, 0, stream>>>(
        m_W1, m_b1, m_g0, m_be0, m_mu0, m_var0, m_g1, m_be1, m_mu1, m_var1,
        f_W1, f_b1, f_g0, f_be0, f_mu0, f_var0, f_g1, f_be1, f_mu1, f_var1,
        mBf, mS1, mT1, mWhi, mWlo,
        fBf, fS1, fT1, fWhi, fWlo);

    fr_kernel<<<8 * N_PTS / 64, 256, 0, stream>>>(
        x, f_W0, f_b0, (const short8*)fWhi, (const short8*)fWlo,
        fBf, fS1, fT1, fr);

    fused_kernel<<<8 * N_PTS / 16, 256, 0, stream>>>(
        x, m_W0, m_b0, (const short8*)mWhi, (const short8*)mWlo,
        mBf, mS1, mT1, fr, (float*)d_out);
}